// Round 1
// baseline (470.290 us; speedup 1.0000x reference)
//
#include <hip/hip_runtime.h>

#define HASH_BUCKETS 1000
#define EMB_DIM 16
#define HDIM 32
#define G4 128   // 4*HDIM
#define TSTEPS 512
#define BATCH 4096

// ---------------------------------------------------------------------------
// Kernel 1: fold embedding table through the input projection.
// P[bucket, 0:128] = emb[bucket, 0:16] @ kernel[0:16, 0:128]
// 1000*128 threads, 16 FMAs each. P (512 KB) lands in L2 for the main kernel.
// ---------------------------------------------------------------------------
__global__ void precompute_P_kernel(const float* __restrict__ emb,
                                    const float* __restrict__ kern,
                                    float* __restrict__ P) {
    int idx = blockIdx.x * blockDim.x + threadIdx.x;
    if (idx >= HASH_BUCKETS * G4) return;
    int row = idx >> 7;      // bucket
    int col = idx & 127;     // gate-column
    float acc = 0.f;
#pragma unroll
    for (int e = 0; e < EMB_DIM; ++e)
        acc = fmaf(emb[row * EMB_DIM + e], kern[e * G4 + col], acc);
    P[idx] = acc;
}

__device__ __forceinline__ float fsigmoid(float x) {
    // safe at extremes: exp(-x)->inf gives 0, exp(-x)->0 gives 1
    return 1.0f / (1.0f + __expf(-x));
}
__device__ __forceinline__ float ftanh(float x) {
    // e in (0,1] -> no inf/NaN; copysign restores sign
    float e = __expf(-2.0f * fabsf(x));
    float t = (1.0f - e) / (1.0f + e);
    return copysignf(t, x);
}

// ---------------------------------------------------------------------------
// Kernel 2: LSTM + MLP head.
// 32 lanes per batch element; lane j owns gate columns {j, j+32, j+64, j+96}
// and the (c[j], h[j]) update. rec_kernel columns held in 128 VGPRs/lane.
// h broadcast between the 32 lanes goes through LDS; the element is fully
// inside one 32-lane half-wave, so no __syncthreads is needed (lockstep wave
// + in-order DS pipe).
// ---------------------------------------------------------------------------
__global__ __launch_bounds__(256, 2)
void lstm_head_kernel(const int* __restrict__ ids,
                      const float* __restrict__ P,
                      const float* __restrict__ R,    // rec_kernel [32][128]
                      const float* __restrict__ w1,   // [32][32]
                      const float* __restrict__ b1,   // [32]
                      const float* __restrict__ w2,   // [32]
                      const float* __restrict__ b2,   // [1]
                      float* __restrict__ out) {
    __shared__ float hsh[8][HDIM];   // 8 elements per 256-thread block

    const int tid = threadIdx.x;
    const int j  = tid & 31;         // gate column within H
    const int el = tid >> 5;         // element slot in block (0..7)
    const int b  = blockIdx.x * 8 + el;
    const int* __restrict__ idrow = ids + b * TSTEPS;

    // R columns {j, j+32, j+64, j+96} for all k -> 128 VGPRs
    float Rreg[HDIM][4];
#pragma unroll
    for (int k = 0; k < HDIM; ++k)
#pragma unroll
        for (int g = 0; g < 4; ++g)
            Rreg[k][g] = R[k * G4 + g * 32 + j];

    float c = 0.f, h = 0.f;
    hsh[el][j] = 0.f;

    // software pipeline: xz one step ahead, ids two steps ahead
    int id_n = idrow[0];
    float xz_c[4];
    {
        const float* Pr = P + id_n * G4 + j;
#pragma unroll
        for (int g = 0; g < 4; ++g) xz_c[g] = Pr[g * 32];
    }
    id_n = (TSTEPS > 1) ? idrow[1] : id_n;

    for (int t = 0; t < TSTEPS; ++t) {
        // issue next-step gather early (L2-resident P)
        float xz_n[4];
        {
            const float* Pr = P + id_n * G4 + j;
#pragma unroll
            for (int g = 0; g < 4; ++g) xz_n[g] = Pr[g * 32];
        }
        int id_nn = idrow[(t + 2 < TSTEPS) ? (t + 2) : (TSTEPS - 1)];

        // broadcast-read full h vector of my element (float4 x8, LDS)
        float4 hv[8];
#pragma unroll
        for (int q = 0; q < 8; ++q)
            hv[q] = *((const float4*)&hsh[el][0] + q);
        const float* hp = (const float*)hv;

        float z0 = xz_c[0], z1 = xz_c[1], z2 = xz_c[2], z3 = xz_c[3];
#pragma unroll
        for (int k = 0; k < HDIM; ++k) {
            float hk = hp[k];
            z0 = fmaf(hk, Rreg[k][0], z0);
            z1 = fmaf(hk, Rreg[k][1], z1);
            z2 = fmaf(hk, Rreg[k][2], z2);
            z3 = fmaf(hk, Rreg[k][3], z3);
        }

        float ig = fsigmoid(z0);
        float fg = fsigmoid(z1);
        float cc = ftanh(z2);
        float og = fsigmoid(z3);
        c = fmaf(fg, c, ig * cc);
        h = og * ftanh(c);

        hsh[el][j] = h;   // publish for next step (in-wave, no barrier)

#pragma unroll
        for (int g = 0; g < 4; ++g) xz_c[g] = xz_n[g];
        id_n = id_nn;
    }

    // ---- MLP head: y = relu(h @ w1 + b1); out = y @ w2 + b2 ----
    float4 hv[8];
#pragma unroll
    for (int q = 0; q < 8; ++q)
        hv[q] = *((const float4*)&hsh[el][0] + q);
    const float* hp = (const float*)hv;

    float y = b1[j];
#pragma unroll
    for (int k = 0; k < HDIM; ++k)
        y = fmaf(hp[k], w1[k * HDIM + j], y);
    y = fmaxf(y, 0.f);

    float v = y * w2[j];
    // reduce across the 32-lane group (xor offsets < 32 stay in-half)
#pragma unroll
    for (int off = 16; off >= 1; off >>= 1)
        v += __shfl_xor(v, off);

    if (j == 0) out[b] = v + b2[0];
}

extern "C" void kernel_launch(void* const* d_in, const int* in_sizes, int n_in,
                              void* d_out, int out_size, void* d_ws, size_t ws_size,
                              hipStream_t stream) {
    const int*   ids  = (const int*)d_in[0];
    const float* emb  = (const float*)d_in[1];
    const float* kern = (const float*)d_in[2];
    const float* rec  = (const float*)d_in[3];
    const float* w1   = (const float*)d_in[4];
    const float* b1   = (const float*)d_in[5];
    const float* w2   = (const float*)d_in[6];
    const float* b2   = (const float*)d_in[7];
    float* out = (float*)d_out;
    float* P   = (float*)d_ws;   // 1000*128*4 = 512 KB scratch

    precompute_P_kernel<<<(HASH_BUCKETS * G4 + 255) / 256, 256, 0, stream>>>(
        emb, kern, P);
    lstm_head_kernel<<<BATCH / 8, 256, 0, stream>>>(
        ids, P, rec, w1, b1, w2, b2, out);
}

// Round 2
// 416.542 us; speedup vs baseline: 1.1290x; 1.1290x over previous
//
#include <hip/hip_runtime.h>

typedef float f32x2 __attribute__((ext_vector_type(2)));

#define HASH_BUCKETS 1000
#define EMB_DIM 16
#define HDIM 32
#define G4 128   // 4*HDIM
#define TSTEPS 512
#define BATCH 4096

// d = a*b + d  (packed 2x fp32, full-rate on CDNA)
#define PK_FMA(z, a, b) \
    asm("v_pk_fma_f32 %0, %1, %2, %0" : "+v"(z) : "v"(a), "v"(b))

// ---------------------------------------------------------------------------
// Kernel 1: fold embedding through input projection, TRANSPOSED layout:
// P2[bucket][j][g] = sum_e emb[bucket][e] * kernel[e][g*32 + j]
// so the main kernel's per-step gather is ONE global_load_dwordx4 per lane.
// ---------------------------------------------------------------------------
__global__ void precompute_P2_kernel(const float* __restrict__ emb,
                                     const float* __restrict__ kern,
                                     float* __restrict__ P2) {
    int idx = blockIdx.x * blockDim.x + threadIdx.x;
    if (idx >= HASH_BUCKETS * G4) return;
    int row = idx >> 7;            // bucket
    int c2  = idx & 127;           // j*4 + g
    int j = c2 >> 2;
    int g = c2 & 3;
    int kcol = g * 32 + j;
    float acc = 0.f;
#pragma unroll
    for (int e = 0; e < EMB_DIM; ++e)
        acc = fmaf(emb[row * EMB_DIM + e], kern[e * G4 + kcol], acc);
    P2[idx] = acc;
}

__device__ __forceinline__ float fsigmoid(float x) {
    return 1.0f / (1.0f + __expf(-x));
}
__device__ __forceinline__ float ftanh(float x) {
    float e = __expf(-2.0f * fabsf(x));
    float t = (1.0f - e) / (1.0f + e);
    return copysignf(t, x);
}

// ---------------------------------------------------------------------------
// Kernel 2: LSTM + MLP head. 32 lanes per batch element; lane j owns gate
// columns {i,f,c,o}[j] and the (c[j],h[j]) update. rec_kernel pinned in
// 128 VGPRs as k-pairs for v_pk_fma_f32. h broadcast via LDS, barrier-free
// (element lives in one 32-lane half-wave).
// ---------------------------------------------------------------------------
__global__ __launch_bounds__(256, 2)
void lstm_head_kernel(const int* __restrict__ ids,
                      const float* __restrict__ P2,   // [1000][32][4]
                      const float* __restrict__ R,    // rec_kernel [32][128]
                      const float* __restrict__ w1,   // [32][32]
                      const float* __restrict__ b1,   // [32]
                      const float* __restrict__ w2,   // [32]
                      const float* __restrict__ b2,   // [1]
                      float* __restrict__ out) {
    __shared__ float hsh[8][HDIM];

    const int tid = threadIdx.x;
    const int j  = tid & 31;
    const int el = tid >> 5;
    const int b  = blockIdx.x * 8 + el;
    const int* __restrict__ idrow = ids + b * TSTEPS;

    // R k-pairs: Rp[k2][g] = (R[2k2][g*32+j], R[2k2+1][g*32+j])
    f32x2 Rp[16][4];
#pragma unroll
    for (int k2 = 0; k2 < 16; ++k2) {
#pragma unroll
        for (int g = 0; g < 4; ++g) {
            f32x2 v;
            v.x = R[(2 * k2)     * G4 + g * 32 + j];
            v.y = R[(2 * k2 + 1) * G4 + g * 32 + j];
            Rp[k2][g] = v;
        }
    }
    // Pin in VGPRs: asm result cannot be rematerialized -> no per-step reloads.
#pragma unroll
    for (int k2 = 0; k2 < 16; ++k2)
#pragma unroll
        for (int g = 0; g < 4; ++g)
            asm("" : "+v"(Rp[k2][g]));

    float c = 0.f, h = 0.f;
    hsh[el][j] = 0.f;

    int id_n = idrow[0];
    float4 xz_c = *(const float4*)(P2 + id_n * G4 + j * 4);
    id_n = idrow[1];

    for (int t = 0; t < TSTEPS; ++t) {
        // prefetch next step's xz (L2-resident P2) and next-next id
        float4 xz_n = *(const float4*)(P2 + id_n * G4 + j * 4);
        int id_nn = idrow[(t + 2 < TSTEPS) ? (t + 2) : (TSTEPS - 1)];

        // broadcast-read my element's h vector (8x ds_read_b128)
        float4 hv4[8];
#pragma unroll
        for (int q = 0; q < 8; ++q)
            hv4[q] = *((const float4*)&hsh[el][0] + q);
        const f32x2* hp2 = (const f32x2*)hv4;

        f32x2 z0, z1, z2, z3;
        z0.x = xz_c.x; z0.y = 0.f;
        z1.x = xz_c.y; z1.y = 0.f;
        z2.x = xz_c.z; z2.y = 0.f;
        z3.x = xz_c.w; z3.y = 0.f;
#pragma unroll
        for (int k2 = 0; k2 < 16; ++k2) {
            f32x2 hh = hp2[k2];
            PK_FMA(z0, hh, Rp[k2][0]);
            PK_FMA(z1, hh, Rp[k2][1]);
            PK_FMA(z2, hh, Rp[k2][2]);
            PK_FMA(z3, hh, Rp[k2][3]);
        }
        float zi = z0.x + z0.y;
        float zf = z1.x + z1.y;
        float zc = z2.x + z2.y;
        float zo = z3.x + z3.y;

        float ig = fsigmoid(zi);
        float fg = fsigmoid(zf);
        float cc = ftanh(zc);
        float og = fsigmoid(zo);
        c = fmaf(fg, c, ig * cc);
        h = og * ftanh(c);

        hsh[el][j] = h;   // in-wave publish, no barrier needed

        xz_c = xz_n;
        id_n = id_nn;
    }

    // ---- MLP head ----
    float4 hv4[8];
#pragma unroll
    for (int q = 0; q < 8; ++q)
        hv4[q] = *((const float4*)&hsh[el][0] + q);
    const float* hp = (const float*)hv4;

    float y = b1[j];
#pragma unroll
    for (int k = 0; k < HDIM; ++k)
        y = fmaf(hp[k], w1[k * HDIM + j], y);
    y = fmaxf(y, 0.f);

    float v = y * w2[j];
#pragma unroll
    for (int off = 16; off >= 1; off >>= 1)
        v += __shfl_xor(v, off);

    if (j == 0) out[b] = v + b2[0];
}

extern "C" void kernel_launch(void* const* d_in, const int* in_sizes, int n_in,
                              void* d_out, int out_size, void* d_ws, size_t ws_size,
                              hipStream_t stream) {
    const int*   ids  = (const int*)d_in[0];
    const float* emb  = (const float*)d_in[1];
    const float* kern = (const float*)d_in[2];
    const float* rec  = (const float*)d_in[3];
    const float* w1   = (const float*)d_in[4];
    const float* b1   = (const float*)d_in[5];
    const float* w2   = (const float*)d_in[6];
    const float* b2   = (const float*)d_in[7];
    float* out = (float*)d_out;
    float* P2  = (float*)d_ws;   // 1000*128*4 B = 512 KB scratch

    precompute_P2_kernel<<<(HASH_BUCKETS * G4 + 255) / 256, 256, 0, stream>>>(
        emb, kern, P2);
    lstm_head_kernel<<<BATCH / 8, 256, 0, stream>>>(
        ids, P2, rec, w1, b1, w2, b2, out);
}

// Round 3
// 390.146 us; speedup vs baseline: 1.2054x; 1.0677x over previous
//
#include <hip/hip_runtime.h>

typedef float f32x2 __attribute__((ext_vector_type(2)));

#define HASH_BUCKETS 1000
#define EMB_DIM 16
#define HDIM 32
#define G4 128   // 4*HDIM
#define TSTEPS 512
#define BATCH 4096

// d = a*b + d  (packed 2x fp32, full-rate on CDNA)
#define PK_FMA(z, a, b) \
    asm("v_pk_fma_f32 %0, %1, %2, %0" : "+v"(z) : "v"(a), "v"(b))

// ---------------------------------------------------------------------------
// Kernel 1: fold embedding through input projection, transposed layout:
// P2[bucket][j][g] = sum_e emb[bucket][e] * kernel[e][g*32 + j]
// ---------------------------------------------------------------------------
__global__ void precompute_P2_kernel(const float* __restrict__ emb,
                                     const float* __restrict__ kern,
                                     float* __restrict__ P2) {
    int idx = blockIdx.x * blockDim.x + threadIdx.x;
    if (idx >= HASH_BUCKETS * G4) return;
    int row = idx >> 7;
    int c2  = idx & 127;
    int j = c2 >> 2;
    int g = c2 & 3;
    float acc = 0.f;
#pragma unroll
    for (int e = 0; e < EMB_DIM; ++e)
        acc = fmaf(emb[row * EMB_DIM + e], kern[e * G4 + g * 32 + j], acc);
    P2[idx] = acc;
}

__device__ __forceinline__ float frcp(float x) {
    float r;
    asm("v_rcp_f32 %0, %1" : "=v"(r) : "v"(x));
    return r;
}
__device__ __forceinline__ float fsigmoid(float x) {
    return frcp(1.0f + __expf(-x));          // rcp(1+e^-x), ~1ulp rcp
}
__device__ __forceinline__ float ftanh(float x) {
    float e = __expf(-2.0f * fabsf(x));      // e in (0,1]
    return copysignf((1.0f - e) * frcp(1.0f + e), x);
}

// ---------------------------------------------------------------------------
// Kernel 2: LSTM + MLP head.
// Wave = 2 batch elements. Lane (j, h): h = lane>>5.
//   - matvec phase: k-half [16h, 16h+16) for BOTH elements -> R footprint
//     64 VGPRs (4 gate-cols x 8 k-pairs), reused across the 2 elements.
//   - xz init: lane loads xz of element h, seeds its element-h partial;
//     element-(1-h) partial seeds 0. One shfl_xor(32) per gate merges halves.
//   - gate/cell phase: lane owns column j of element h (amortized: 2 el/wave).
// All communication in-wave (LDS h-staging + shfl) -> no barriers.
// ---------------------------------------------------------------------------
__global__ __launch_bounds__(256, 2)
void lstm_head_kernel(const int* __restrict__ ids,
                      const float* __restrict__ P2,   // [1000][32][4]
                      const float* __restrict__ R,    // rec_kernel [32][128]
                      const float* __restrict__ w1,   // [32][32]
                      const float* __restrict__ b1,   // [32]
                      const float* __restrict__ w2,   // [32]
                      const float* __restrict__ b2,   // [1]
                      float* __restrict__ out) {
    __shared__ float hsh[8][HDIM];   // 8 elements per 256-thread block

    const int tid = threadIdx.x;
    const int wl  = tid & 63;
    const int j   = wl & 31;         // gate-col group
    const int h_  = wl >> 5;         // k-half AND owned-element selector
    const int w   = tid >> 6;        // wave slot in block
    const int elm = 2 * w + h_;      // my element slot (gates/cell)
    const int elo = 2 * w + 1 - h_;  // other element slot
    const int bb  = blockIdx.x * 8;  // block batch base
    const int* __restrict__ idm = ids + (bb + elm) * TSTEPS;

    const int k0 = h_ * 16;

    // R k-pairs for my k-half: Rp[k2][g] = (R[k0+2k2][g*32+j], R[k0+2k2+1][..])
    f32x2 Rp[8][4];
#pragma unroll
    for (int k2 = 0; k2 < 8; ++k2) {
#pragma unroll
        for (int g = 0; g < 4; ++g) {
            f32x2 v;
            v.x = R[(k0 + 2 * k2)     * G4 + g * 32 + j];
            v.y = R[(k0 + 2 * k2 + 1) * G4 + g * 32 + j];
            Rp[k2][g] = v;
        }
    }

    float cst = 0.f;
    hsh[elm][j] = 0.f;   // each half zeroes its own element row

    int id_n = idm[0];
    float4 xz_c = *(const float4*)(P2 + id_n * G4 + j * 4);
    id_n = idm[1];

    const float* hm_base = &hsh[elm][k0];
    const float* ho_base = &hsh[elo][k0];

    for (int t = 0; t < TSTEPS; ++t) {
        // prefetch next-step xz (L2-resident P2) and next-next id
        float4 xz_n = *(const float4*)(P2 + id_n * G4 + j * 4);
        int id_nn = idm[(t + 2 < TSTEPS) ? (t + 2) : (TSTEPS - 1)];

        // my k-half of h for both elements (4x ds_read_b128 each)
        float4 hmv[4], hov[4];
#pragma unroll
        for (int q = 0; q < 4; ++q) {
            hmv[q] = ((const float4*)hm_base)[q];
            hov[q] = ((const float4*)ho_base)[q];
        }
        const f32x2* hm = (const f32x2*)hmv;
        const f32x2* ho = (const f32x2*)hov;

        f32x2 zm[4], zo[4];
        zm[0].x = xz_c.x; zm[0].y = 0.f;
        zm[1].x = xz_c.y; zm[1].y = 0.f;
        zm[2].x = xz_c.z; zm[2].y = 0.f;
        zm[3].x = xz_c.w; zm[3].y = 0.f;
#pragma unroll
        for (int g = 0; g < 4; ++g) { zo[g].x = 0.f; zo[g].y = 0.f; }

#pragma unroll
        for (int k2 = 0; k2 < 8; ++k2) {
            f32x2 a = hm[k2];
            f32x2 o = ho[k2];
            PK_FMA(zm[0], a, Rp[k2][0]);
            PK_FMA(zm[1], a, Rp[k2][1]);
            PK_FMA(zm[2], a, Rp[k2][2]);
            PK_FMA(zm[3], a, Rp[k2][3]);
            PK_FMA(zo[0], o, Rp[k2][0]);
            PK_FMA(zo[1], o, Rp[k2][1]);
            PK_FMA(zo[2], o, Rp[k2][2]);
            PK_FMA(zo[3], o, Rp[k2][3]);
        }

        // merge k-halves: my full z = my partial + neighbor's other-partial
        float z[4];
#pragma unroll
        for (int g = 0; g < 4; ++g) {
            float zms = zm[g].x + zm[g].y;
            float zos = zo[g].x + zo[g].y;
            z[g] = zms + __shfl_xor(zos, 32);
        }

        float ig = fsigmoid(z[0]);
        float fg = fsigmoid(z[1]);
        float ct = ftanh(z[2]);
        float og = fsigmoid(z[3]);
        cst = fmaf(fg, cst, ig * ct);
        float hval = og * ftanh(cst);

        hsh[elm][j] = hval;   // in-wave publish, no barrier

        xz_c = xz_n;
        id_n = id_nn;
    }

    // ---- MLP head: y = relu(h @ w1 + b1); out = y @ w2 + b2 ----
    float4 hv4[8];
#pragma unroll
    for (int q = 0; q < 8; ++q)
        hv4[q] = ((const float4*)&hsh[elm][0])[q];
    const float* hp = (const float*)hv4;

    float y = b1[j];
#pragma unroll
    for (int k = 0; k < HDIM; ++k)
        y = fmaf(hp[k], w1[k * HDIM + j], y);
    y = fmaxf(y, 0.f);

    float v = y * w2[j];
#pragma unroll
    for (int off = 16; off >= 1; off >>= 1)
        v += __shfl_xor(v, off);        // stays within the 32-lane half

    if (j == 0) out[bb + elm] = v + b2[0];
}

extern "C" void kernel_launch(void* const* d_in, const int* in_sizes, int n_in,
                              void* d_out, int out_size, void* d_ws, size_t ws_size,
                              hipStream_t stream) {
    const int*   ids  = (const int*)d_in[0];
    const float* emb  = (const float*)d_in[1];
    const float* kern = (const float*)d_in[2];
    const float* rec  = (const float*)d_in[3];
    const float* w1   = (const float*)d_in[4];
    const float* b1   = (const float*)d_in[5];
    const float* w2   = (const float*)d_in[6];
    const float* b2   = (const float*)d_in[7];
    float* out = (float*)d_out;
    float* P2  = (float*)d_ws;   // 1000*128*4 B = 512 KB scratch

    precompute_P2_kernel<<<(HASH_BUCKETS * G4 + 255) / 256, 256, 0, stream>>>(
        emb, kern, P2);
    lstm_head_kernel<<<BATCH / 8, 256, 0, stream>>>(
        ids, P2, rec, w1, b1, w2, b2, out);
}

// Round 4
// 369.354 us; speedup vs baseline: 1.2733x; 1.0563x over previous
//
#include <hip/hip_runtime.h>

typedef float f32x2 __attribute__((ext_vector_type(2)));

#define HASH_BUCKETS 1000
#define EMB_DIM 16
#define HDIM 32
#define G4 128   // 4*HDIM
#define TSTEPS 512
#define BATCH 4096

// d = a*b + d  (packed 2x fp32, full-rate on CDNA)
#define PK_FMA(z, a, b) \
    asm("v_pk_fma_f32 %0, %1, %2, %0" : "+v"(z) : "v"(a), "v"(b))
// d = a*b (packed)
#define PK_MUL(z, a, b) \
    asm("v_pk_mul_f32 %0, %1, %2" : "=v"(z) : "v"(a), "v"(b))

// ---------------------------------------------------------------------------
// Kernel 1: fold embedding through input projection, transposed layout:
// P2[bucket][j][g] = sum_e emb[bucket][e] * kernel[e][g*32 + j]
// ---------------------------------------------------------------------------
__global__ void precompute_P2_kernel(const float* __restrict__ emb,
                                     const float* __restrict__ kern,
                                     float* __restrict__ P2) {
    int idx = blockIdx.x * blockDim.x + threadIdx.x;
    if (idx >= HASH_BUCKETS * G4) return;
    int row = idx >> 7;
    int c2  = idx & 127;
    int j = c2 >> 2;
    int g = c2 & 3;
    float acc = 0.f;
#pragma unroll
    for (int e = 0; e < EMB_DIM; ++e)
        acc = fmaf(emb[row * EMB_DIM + e], kern[e * G4 + g * 32 + j], acc);
    P2[idx] = acc;
}

__device__ __forceinline__ float frcp(float x) {
    float r;
    asm("v_rcp_f32 %0, %1" : "=v"(r) : "v"(x));
    return r;
}
__device__ __forceinline__ float fsigmoid(float x) {
    return frcp(1.0f + __expf(-x));          // rcp(1+e^-x)
}
__device__ __forceinline__ float ftanh(float x) {
    float e = __expf(-2.0f * fabsf(x));      // e in (0,1] -> no inf/NaN
    return copysignf((1.0f - e) * frcp(1.0f + e), x);
}

// ---------------------------------------------------------------------------
// Kernel 2: LSTM + MLP head.
// Wave = 2 batch elements. Lane (j, h_): h_ = lane>>5.
//   - matvec: k-half [16h_,16h_+16) for BOTH elements; R footprint 64 VGPRs.
//   - merge halves with one shfl_xor(32) per gate.
//   - gates/cell: lane owns column j of element h_.
// All communication in-wave -> barrier-free.
// amdgpu_waves_per_eu(2,2): grid gives exactly 2 waves/SIMD, so pin the
// occupancy target there -> 256-VGPR budget -> no AGPR-homing of Rp
// (round-3 pathology: compiler targeted 4 waves/EU, spilled Rp to AGPRs,
// paid v_accvgpr_read copies at every PK_FMA).
// ---------------------------------------------------------------------------
__global__ __launch_bounds__(256)
__attribute__((amdgpu_waves_per_eu(2, 2)))
void lstm_head_kernel(const int* __restrict__ ids,
                      const float* __restrict__ P2,   // [1000][32][4]
                      const float* __restrict__ R,    // rec_kernel [32][128]
                      const float* __restrict__ w1,   // [32][32]
                      const float* __restrict__ b1,   // [32]
                      const float* __restrict__ w2,   // [32]
                      const float* __restrict__ b2,   // [1]
                      float* __restrict__ out) {
    __shared__ float hsh[8][HDIM];

    const int tid = threadIdx.x;
    const int wl  = tid & 63;
    const int j   = wl & 31;         // gate-col group
    const int h_  = wl >> 5;         // k-half AND owned-element selector
    const int w   = tid >> 6;        // wave slot in block
    const int elm = 2 * w + h_;      // my element slot
    const int elo = 2 * w + 1 - h_;  // other element slot
    const int bb  = blockIdx.x * 8;
    const int* __restrict__ idm = ids + (bb + elm) * TSTEPS;

    const int k0 = h_ * 16;

    // R k-pairs for my k-half
    f32x2 Rp[8][4];
#pragma unroll
    for (int k2 = 0; k2 < 8; ++k2) {
#pragma unroll
        for (int g = 0; g < 4; ++g) {
            f32x2 v;
            v.x = R[(k0 + 2 * k2)     * G4 + g * 32 + j];
            v.y = R[(k0 + 2 * k2 + 1) * G4 + g * 32 + j];
            Rp[k2][g] = v;
        }
    }
    // pin: forces materialization, blocks remat-from-global inside the loop
#pragma unroll
    for (int k2 = 0; k2 < 8; ++k2)
#pragma unroll
        for (int g = 0; g < 4; ++g)
            asm("" : "+v"(Rp[k2][g]));

    float cst = 0.f;
    hsh[elm][j] = 0.f;

    int id_n = idm[0];
    float4 xz_c = *(const float4*)(P2 + id_n * G4 + j * 4);
    id_n = idm[1];

    const float* hm_base = &hsh[elm][k0];
    const float* ho_base = &hsh[elo][k0];

    for (int t = 0; t < TSTEPS; ++t) {
        // prefetch next-step xz (L2-resident) and next-next id
        float4 xz_n = *(const float4*)(P2 + id_n * G4 + j * 4);
        int id_nn = idm[(t + 2 < TSTEPS) ? (t + 2) : (TSTEPS - 1)];

        // my k-half of h for both elements (8x ds_read_b128)
        float4 hmv[4], hov[4];
#pragma unroll
        for (int q = 0; q < 4; ++q) {
            hmv[q] = ((const float4*)hm_base)[q];
            hov[q] = ((const float4*)ho_base)[q];
        }
        const f32x2* hm = (const f32x2*)hmv;
        const f32x2* ho = (const f32x2*)hov;

        f32x2 zm[4], zo[4];
        zm[0].x = xz_c.x; zm[0].y = 0.f;
        zm[1].x = xz_c.y; zm[1].y = 0.f;
        zm[2].x = xz_c.z; zm[2].y = 0.f;
        zm[3].x = xz_c.w; zm[3].y = 0.f;

        // k2 = 0: seed zo with pk_mul (saves 8 v_mov of zero-init)
        {
            f32x2 a = hm[0], o = ho[0];
            PK_FMA(zm[0], a, Rp[0][0]);
            PK_FMA(zm[1], a, Rp[0][1]);
            PK_FMA(zm[2], a, Rp[0][2]);
            PK_FMA(zm[3], a, Rp[0][3]);
            PK_MUL(zo[0], o, Rp[0][0]);
            PK_MUL(zo[1], o, Rp[0][1]);
            PK_MUL(zo[2], o, Rp[0][2]);
            PK_MUL(zo[3], o, Rp[0][3]);
        }
#pragma unroll
        for (int k2 = 1; k2 < 8; ++k2) {
            f32x2 a = hm[k2];
            f32x2 o = ho[k2];
            PK_FMA(zm[0], a, Rp[k2][0]);
            PK_FMA(zm[1], a, Rp[k2][1]);
            PK_FMA(zm[2], a, Rp[k2][2]);
            PK_FMA(zm[3], a, Rp[k2][3]);
            PK_FMA(zo[0], o, Rp[k2][0]);
            PK_FMA(zo[1], o, Rp[k2][1]);
            PK_FMA(zo[2], o, Rp[k2][2]);
            PK_FMA(zo[3], o, Rp[k2][3]);
        }

        // merge k-halves
        float z[4];
#pragma unroll
        for (int g = 0; g < 4; ++g) {
            float zms = zm[g].x + zm[g].y;
            float zos = zo[g].x + zo[g].y;
            z[g] = zms + __shfl_xor(zos, 32);
        }

        float ig = fsigmoid(z[0]);
        float fg = fsigmoid(z[1]);
        float ct = ftanh(z[2]);
        float og = fsigmoid(z[3]);
        cst = fmaf(fg, cst, ig * ct);
        float hval = og * ftanh(cst);

        hsh[elm][j] = hval;   // in-wave publish, no barrier

        xz_c = xz_n;
        id_n = id_nn;
    }

    // ---- MLP head ----
    float4 hv4[8];
#pragma unroll
    for (int q = 0; q < 8; ++q)
        hv4[q] = ((const float4*)&hsh[elm][0])[q];
    const float* hp = (const float*)hv4;

    float y = b1[j];
#pragma unroll
    for (int k = 0; k < HDIM; ++k)
        y = fmaf(hp[k], w1[k * HDIM + j], y);
    y = fmaxf(y, 0.f);

    float v = y * w2[j];
#pragma unroll
    for (int off = 16; off >= 1; off >>= 1)
        v += __shfl_xor(v, off);        // stays within the 32-lane half

    if (j == 0) out[bb + elm] = v + b2[0];
}

extern "C" void kernel_launch(void* const* d_in, const int* in_sizes, int n_in,
                              void* d_out, int out_size, void* d_ws, size_t ws_size,
                              hipStream_t stream) {
    const int*   ids  = (const int*)d_in[0];
    const float* emb  = (const float*)d_in[1];
    const float* kern = (const float*)d_in[2];
    const float* rec  = (const float*)d_in[3];
    const float* w1   = (const float*)d_in[4];
    const float* b1   = (const float*)d_in[5];
    const float* w2   = (const float*)d_in[6];
    const float* b2   = (const float*)d_in[7];
    float* out = (float*)d_out;
    float* P2  = (float*)d_ws;   // 512 KB scratch

    precompute_P2_kernel<<<(HASH_BUCKETS * G4 + 255) / 256, 256, 0, stream>>>(
        emb, kern, P2);
    lstm_head_kernel<<<BATCH / 8, 256, 0, stream>>>(
        ids, P2, rec, w1, b1, w2, b2, out);
}

// Round 7
// 361.521 us; speedup vs baseline: 1.3009x; 1.0217x over previous
//
#include <hip/hip_runtime.h>
#include <stdint.h>

#define HASH_BUCKETS 1000
#define EMB_DIM 16
#define HDIM 32
#define G4 128   // 4*HDIM
#define TSTEPS 512
#define BATCH 4096

// ---------------------------------------------------------------------------
// Kernel 1: fold embedding through input projection, transposed layout:
// P2[bucket][j][g] = sum_e emb[bucket][e] * kernel[e][g*32 + j]
// ---------------------------------------------------------------------------
__global__ void precompute_P2_kernel(const float* __restrict__ emb,
                                     const float* __restrict__ kern,
                                     float* __restrict__ P2) {
    int idx = blockIdx.x * blockDim.x + threadIdx.x;
    if (idx >= HASH_BUCKETS * G4) return;
    int row = idx >> 7;
    int c2  = idx & 127;
    int j = c2 >> 2;
    int g = c2 & 3;
    float acc = 0.f;
#pragma unroll
    for (int e = 0; e < EMB_DIM; ++e)
        acc = fmaf(emb[row * EMB_DIM + e], kern[e * G4 + g * 32 + j], acc);
    P2[idx] = acc;
}

// ---------------------------------------------------------------------------
// Kernel 2: LSTM + MLP head. Whole 512-step recurrence in ONE asm block with
// hard-coded physical registers (v40-v180, clobbered) -> compiler cannot
// AGPR-home the loop-invariant R fragments (rounds 2-5 pathology).
// Round-7 fix: CDNA requires manually-inserted wait states between a VALU
// transcendental (v_exp/v_rcp) and a dependent VALU read. Gate math is now
// batched 4-wide (>=3 intervening instrs for every trans result) and the
// serial tanh(c) chain is padded with s_nop 1.
// Register map:
//   v40-103 : R k-pairs (8 k2 x 4 gates x f32x2)    [loop-invariant]
//   v104-119: hm (my element)   v120-135: ho (other element)
//   v136-143: zm partials       v144-151: zo partials
//   v152-155: xz current        v156-159: xz next (prefetch)
//   v160: id next  v161: id next-next  v162: ids voffset  v163: voff clamp
//   v164: hm addr  v165: ho addr  v166: h write addr  v167: bpermute addr
//   v168: j*16     v169-172: z[4]   v173-178: gate scratch
//   v179: cell state   v180: h
// ---------------------------------------------------------------------------
__global__ __launch_bounds__(256)
__attribute__((amdgpu_waves_per_eu(2, 2)))
void lstm_head_kernel(const int* __restrict__ ids,
                      const float* __restrict__ P2,   // [1000][32][4]
                      const float* __restrict__ R,    // rec_kernel [32][128]
                      const float* __restrict__ w1,   // [32][32]
                      const float* __restrict__ b1,   // [32]
                      const float* __restrict__ w2,   // [32]
                      const float* __restrict__ b2,   // [1]
                      float* __restrict__ out) {
    __shared__ __align__(16) float hsh[8][HDIM];
    __shared__ float2 Rlds[2048];   // [k2abs:16][g:4][j:32] k-pairs of R

    const int tid = threadIdx.x;
    const int wl  = tid & 63;
    const int j   = wl & 31;
    const int h_  = wl >> 5;
    const int w   = tid >> 6;
    const int elm = 2 * w + h_;
    const int elo = 2 * w + 1 - h_;
    const int bb  = blockIdx.x * 8;
    const int k0  = h_ * 16;

    // stage R as k-pairs into LDS
    for (int idx = tid; idx < 2048; idx += 256) {
        int k2a = idx >> 7;
        int col = idx & 127;
        Rlds[idx] = make_float2(R[(2 * k2a) * G4 + col],
                                R[(2 * k2a + 1) * G4 + col]);
    }
    hsh[elm][j] = 0.f;
    __syncthreads();

    uint32_t hsh_base = (uint32_t)(uintptr_t)(&hsh[0][0]);
    uint32_t r_base   = (uint32_t)(uintptr_t)(&Rlds[0]);
    uint32_t hma   = hsh_base + (uint32_t)((elm * HDIM + k0) * 4);
    uint32_t hoa   = hsh_base + (uint32_t)((elo * HDIM + k0) * 4);
    uint32_t hwa   = hsh_base + (uint32_t)((elm * HDIM + j) * 4);
    uint32_t pma   = (uint32_t)((wl ^ 32) * 4);
    uint32_t j16   = (uint32_t)(j * 16);
    uint32_t rbase = r_base + (uint32_t)(h_ * 8192 + j * 8);

    const int* __restrict__ idrow = ids + (size_t)(bb + elm) * TSTEPS;
    int id0 = idrow[0];
    int id1 = idrow[1];
    float4 xz0 = *(const float4*)(P2 + id0 * G4 + j * 4);
    uint32_t voff0 = (uint32_t)(((bb + elm) * TSTEPS + 1) * 4);
    uint32_t vmax  = (uint32_t)(((bb + elm) * TSTEPS + 511) * 4);

    asm volatile(
        "v_mov_b32 v164, %[hma]\n\t"
        "v_mov_b32 v165, %[hoa]\n\t"
        "v_mov_b32 v166, %[hwa]\n\t"
        "v_mov_b32 v167, %[pma]\n\t"
        "v_mov_b32 v168, %[j16]\n\t"
        "v_mov_b32 v162, %[voff0]\n\t"
        "v_mov_b32 v163, %[vmax]\n\t"
        "v_mov_b32 v152, %[xz0]\n\t"
        "v_mov_b32 v153, %[xz1]\n\t"
        "v_mov_b32 v154, %[xz2]\n\t"
        "v_mov_b32 v155, %[xz3]\n\t"
        "v_mov_b32 v160, %[id1]\n\t"
        "v_mov_b32 v104, %[rbase]\n\t"
        "v_mov_b32 v179, 0\n\t"
        "ds_read_b64 v[40:41], v104\n\t"
        "ds_read_b64 v[42:43], v104 offset:256\n\t"
        "ds_read_b64 v[44:45], v104 offset:512\n\t"
        "ds_read_b64 v[46:47], v104 offset:768\n\t"
        "ds_read_b64 v[48:49], v104 offset:1024\n\t"
        "ds_read_b64 v[50:51], v104 offset:1280\n\t"
        "ds_read_b64 v[52:53], v104 offset:1536\n\t"
        "ds_read_b64 v[54:55], v104 offset:1792\n\t"
        "ds_read_b64 v[56:57], v104 offset:2048\n\t"
        "ds_read_b64 v[58:59], v104 offset:2304\n\t"
        "ds_read_b64 v[60:61], v104 offset:2560\n\t"
        "ds_read_b64 v[62:63], v104 offset:2816\n\t"
        "ds_read_b64 v[64:65], v104 offset:3072\n\t"
        "ds_read_b64 v[66:67], v104 offset:3328\n\t"
        "ds_read_b64 v[68:69], v104 offset:3584\n\t"
        "ds_read_b64 v[70:71], v104 offset:3840\n\t"
        "ds_read_b64 v[72:73], v104 offset:4096\n\t"
        "ds_read_b64 v[74:75], v104 offset:4352\n\t"
        "ds_read_b64 v[76:77], v104 offset:4608\n\t"
        "ds_read_b64 v[78:79], v104 offset:4864\n\t"
        "ds_read_b64 v[80:81], v104 offset:5120\n\t"
        "ds_read_b64 v[82:83], v104 offset:5376\n\t"
        "ds_read_b64 v[84:85], v104 offset:5632\n\t"
        "ds_read_b64 v[86:87], v104 offset:5888\n\t"
        "ds_read_b64 v[88:89], v104 offset:6144\n\t"
        "ds_read_b64 v[90:91], v104 offset:6400\n\t"
        "ds_read_b64 v[92:93], v104 offset:6656\n\t"
        "ds_read_b64 v[94:95], v104 offset:6912\n\t"
        "ds_read_b64 v[96:97], v104 offset:7168\n\t"
        "ds_read_b64 v[98:99], v104 offset:7424\n\t"
        "ds_read_b64 v[100:101], v104 offset:7680\n\t"
        "ds_read_b64 v[102:103], v104 offset:7936\n\t"
        "s_movk_i32 s60, 0x200\n\t"
        "s_waitcnt lgkmcnt(0)\n\t"
        "Llstm_%=:\n\t"
        "v_lshl_add_u32 v169, v160, 9, v168\n\t"
        "global_load_dwordx4 v[156:159], v169, %[P2]\n\t"
        "v_add_u32 v162, 4, v162\n\t"
        "v_min_u32 v162, v162, v163\n\t"
        "global_load_dword v161, v162, %[IDS]\n\t"
        "ds_read_b128 v[104:107], v164\n\t"
        "ds_read_b128 v[108:111], v164 offset:16\n\t"
        "ds_read_b128 v[112:115], v164 offset:32\n\t"
        "ds_read_b128 v[116:119], v164 offset:48\n\t"
        "ds_read_b128 v[120:123], v165\n\t"
        "ds_read_b128 v[124:127], v165 offset:16\n\t"
        "ds_read_b128 v[128:131], v165 offset:32\n\t"
        "ds_read_b128 v[132:135], v165 offset:48\n\t"
        "s_waitcnt lgkmcnt(0)\n\t"
        "v_pk_mul_f32 v[136:137], v[104:105], v[40:41]\n\t"
        "v_pk_mul_f32 v[138:139], v[104:105], v[42:43]\n\t"
        "v_pk_mul_f32 v[140:141], v[104:105], v[44:45]\n\t"
        "v_pk_mul_f32 v[142:143], v[104:105], v[46:47]\n\t"
        "v_pk_mul_f32 v[144:145], v[120:121], v[40:41]\n\t"
        "v_pk_mul_f32 v[146:147], v[120:121], v[42:43]\n\t"
        "v_pk_mul_f32 v[148:149], v[120:121], v[44:45]\n\t"
        "v_pk_mul_f32 v[150:151], v[120:121], v[46:47]\n\t"
        "v_pk_fma_f32 v[136:137], v[106:107], v[48:49], v[136:137]\n\t"
        "v_pk_fma_f32 v[138:139], v[106:107], v[50:51], v[138:139]\n\t"
        "v_pk_fma_f32 v[140:141], v[106:107], v[52:53], v[140:141]\n\t"
        "v_pk_fma_f32 v[142:143], v[106:107], v[54:55], v[142:143]\n\t"
        "v_pk_fma_f32 v[144:145], v[122:123], v[48:49], v[144:145]\n\t"
        "v_pk_fma_f32 v[146:147], v[122:123], v[50:51], v[146:147]\n\t"
        "v_pk_fma_f32 v[148:149], v[122:123], v[52:53], v[148:149]\n\t"
        "v_pk_fma_f32 v[150:151], v[122:123], v[54:55], v[150:151]\n\t"
        "v_pk_fma_f32 v[136:137], v[108:109], v[56:57], v[136:137]\n\t"
        "v_pk_fma_f32 v[138:139], v[108:109], v[58:59], v[138:139]\n\t"
        "v_pk_fma_f32 v[140:141], v[108:109], v[60:61], v[140:141]\n\t"
        "v_pk_fma_f32 v[142:143], v[108:109], v[62:63], v[142:143]\n\t"
        "v_pk_fma_f32 v[144:145], v[124:125], v[56:57], v[144:145]\n\t"
        "v_pk_fma_f32 v[146:147], v[124:125], v[58:59], v[146:147]\n\t"
        "v_pk_fma_f32 v[148:149], v[124:125], v[60:61], v[148:149]\n\t"
        "v_pk_fma_f32 v[150:151], v[124:125], v[62:63], v[150:151]\n\t"
        "v_pk_fma_f32 v[136:137], v[110:111], v[64:65], v[136:137]\n\t"
        "v_pk_fma_f32 v[138:139], v[110:111], v[66:67], v[138:139]\n\t"
        "v_pk_fma_f32 v[140:141], v[110:111], v[68:69], v[140:141]\n\t"
        "v_pk_fma_f32 v[142:143], v[110:111], v[70:71], v[142:143]\n\t"
        "v_pk_fma_f32 v[144:145], v[126:127], v[64:65], v[144:145]\n\t"
        "v_pk_fma_f32 v[146:147], v[126:127], v[66:67], v[146:147]\n\t"
        "v_pk_fma_f32 v[148:149], v[126:127], v[68:69], v[148:149]\n\t"
        "v_pk_fma_f32 v[150:151], v[126:127], v[70:71], v[150:151]\n\t"
        "v_pk_fma_f32 v[136:137], v[112:113], v[72:73], v[136:137]\n\t"
        "v_pk_fma_f32 v[138:139], v[112:113], v[74:75], v[138:139]\n\t"
        "v_pk_fma_f32 v[140:141], v[112:113], v[76:77], v[140:141]\n\t"
        "v_pk_fma_f32 v[142:143], v[112:113], v[78:79], v[142:143]\n\t"
        "v_pk_fma_f32 v[144:145], v[128:129], v[72:73], v[144:145]\n\t"
        "v_pk_fma_f32 v[146:147], v[128:129], v[74:75], v[146:147]\n\t"
        "v_pk_fma_f32 v[148:149], v[128:129], v[76:77], v[148:149]\n\t"
        "v_pk_fma_f32 v[150:151], v[128:129], v[78:79], v[150:151]\n\t"
        "v_pk_fma_f32 v[136:137], v[114:115], v[80:81], v[136:137]\n\t"
        "v_pk_fma_f32 v[138:139], v[114:115], v[82:83], v[138:139]\n\t"
        "v_pk_fma_f32 v[140:141], v[114:115], v[84:85], v[140:141]\n\t"
        "v_pk_fma_f32 v[142:143], v[114:115], v[86:87], v[142:143]\n\t"
        "v_pk_fma_f32 v[144:145], v[130:131], v[80:81], v[144:145]\n\t"
        "v_pk_fma_f32 v[146:147], v[130:131], v[82:83], v[146:147]\n\t"
        "v_pk_fma_f32 v[148:149], v[130:131], v[84:85], v[148:149]\n\t"
        "v_pk_fma_f32 v[150:151], v[130:131], v[86:87], v[150:151]\n\t"
        "v_pk_fma_f32 v[136:137], v[116:117], v[88:89], v[136:137]\n\t"
        "v_pk_fma_f32 v[138:139], v[116:117], v[90:91], v[138:139]\n\t"
        "v_pk_fma_f32 v[140:141], v[116:117], v[92:93], v[140:141]\n\t"
        "v_pk_fma_f32 v[142:143], v[116:117], v[94:95], v[142:143]\n\t"
        "v_pk_fma_f32 v[144:145], v[132:133], v[88:89], v[144:145]\n\t"
        "v_pk_fma_f32 v[146:147], v[132:133], v[90:91], v[146:147]\n\t"
        "v_pk_fma_f32 v[148:149], v[132:133], v[92:93], v[148:149]\n\t"
        "v_pk_fma_f32 v[150:151], v[132:133], v[94:95], v[150:151]\n\t"
        "v_pk_fma_f32 v[136:137], v[118:119], v[96:97], v[136:137]\n\t"
        "v_pk_fma_f32 v[138:139], v[118:119], v[98:99], v[138:139]\n\t"
        "v_pk_fma_f32 v[140:141], v[118:119], v[100:101], v[140:141]\n\t"
        "v_pk_fma_f32 v[142:143], v[118:119], v[102:103], v[142:143]\n\t"
        "v_pk_fma_f32 v[144:145], v[134:135], v[96:97], v[144:145]\n\t"
        "v_pk_fma_f32 v[146:147], v[134:135], v[98:99], v[146:147]\n\t"
        "v_pk_fma_f32 v[148:149], v[134:135], v[100:101], v[148:149]\n\t"
        "v_pk_fma_f32 v[150:151], v[134:135], v[102:103], v[150:151]\n\t"
        "v_add_f32 v169, v136, v137\n\t"
        "v_add_f32 v170, v138, v139\n\t"
        "v_add_f32 v171, v140, v141\n\t"
        "v_add_f32 v172, v142, v143\n\t"
        "v_add_f32 v173, v144, v145\n\t"
        "v_add_f32 v174, v146, v147\n\t"
        "v_add_f32 v175, v148, v149\n\t"
        "v_add_f32 v176, v150, v151\n\t"
        "ds_bpermute_b32 v173, v167, v173\n\t"
        "ds_bpermute_b32 v174, v167, v174\n\t"
        "ds_bpermute_b32 v175, v167, v175\n\t"
        "ds_bpermute_b32 v176, v167, v176\n\t"
        "v_add_f32 v169, v169, v152\n\t"
        "v_add_f32 v170, v170, v153\n\t"
        "v_add_f32 v171, v171, v154\n\t"
        "v_add_f32 v172, v172, v155\n\t"
        "s_waitcnt lgkmcnt(0)\n\t"
        "v_add_f32 v169, v169, v173\n\t"
        "v_add_f32 v170, v170, v174\n\t"
        "v_add_f32 v171, v171, v175\n\t"
        "v_add_f32 v172, v172, v176\n\t"
        // gates, hazard-safe: every trans result has >=3 intervening instrs
        "v_mul_f32 v173, 0xbfb8aa3b, v169\n\t"   // i: -log2(e)*z
        "v_mul_f32 v174, 0xbfb8aa3b, v170\n\t"   // f
        "v_mul_f32 v175, 0x4038aa3b, v171\n\t"   // c~: 2log2(e)*z
        "v_mul_f32 v176, 0xbfb8aa3b, v172\n\t"   // o
        "v_exp_f32 v175, v175\n\t"
        "v_exp_f32 v173, v173\n\t"
        "v_exp_f32 v174, v174\n\t"
        "v_exp_f32 v176, v176\n\t"
        "v_add_f32 v175, 1.0, v175\n\t"
        "v_add_f32 v173, 1.0, v173\n\t"
        "v_add_f32 v174, 1.0, v174\n\t"
        "v_add_f32 v176, 1.0, v176\n\t"
        "v_rcp_f32 v175, v175\n\t"
        "v_rcp_f32 v173, v173\n\t"
        "v_rcp_f32 v174, v174\n\t"
        "v_rcp_f32 v176, v176\n\t"
        "v_fma_f32 v175, -2.0, v175, 1.0\n\t"    // tanh(zc)
        "v_mul_f32 v177, v173, v175\n\t"         // i * c~
        "v_fma_f32 v179, v174, v179, v177\n\t"   // c = f*c + i*c~
        "v_mul_f32 v178, 0x4038aa3b, v179\n\t"
        "v_exp_f32 v178, v178\n\t"
        "s_nop 1\n\t"
        "v_add_f32 v178, 1.0, v178\n\t"
        "v_rcp_f32 v178, v178\n\t"
        "s_nop 1\n\t"
        "v_fma_f32 v178, -2.0, v178, 1.0\n\t"    // tanh(c)
        "v_mul_f32 v180, v176, v178\n\t"         // h = o * tanh(c)
        "ds_write_b32 v166, v180\n\t"
        "s_waitcnt vmcnt(0)\n\t"
        "v_mov_b32 v152, v156\n\t"
        "v_mov_b32 v153, v157\n\t"
        "v_mov_b32 v154, v158\n\t"
        "v_mov_b32 v155, v159\n\t"
        "v_mov_b32 v160, v161\n\t"
        "s_addk_i32 s60, -1\n\t"
        "s_cmp_lg_u32 s60, 0\n\t"
        "s_cbranch_scc1 Llstm_%=\n\t"
        "s_waitcnt vmcnt(0) lgkmcnt(0)\n\t"
        :
        : [hma]"v"(hma), [hoa]"v"(hoa), [hwa]"v"(hwa), [pma]"v"(pma),
          [j16]"v"(j16), [voff0]"v"(voff0), [vmax]"v"(vmax),
          [rbase]"v"(rbase),
          [xz0]"v"(xz0.x), [xz1]"v"(xz0.y), [xz2]"v"(xz0.z), [xz3]"v"(xz0.w),
          [id1]"v"(id1), [P2]"s"(P2), [IDS]"s"(ids)
        : "v40","v41","v42","v43","v44","v45","v46","v47","v48","v49",
          "v50","v51","v52","v53","v54","v55","v56","v57","v58","v59",
          "v60","v61","v62","v63","v64","v65","v66","v67","v68","v69",
          "v70","v71","v72","v73","v74","v75","v76","v77","v78","v79",
          "v80","v81","v82","v83","v84","v85","v86","v87","v88","v89",
          "v90","v91","v92","v93","v94","v95","v96","v97","v98","v99",
          "v100","v101","v102","v103","v104","v105","v106","v107","v108","v109",
          "v110","v111","v112","v113","v114","v115","v116","v117","v118","v119",
          "v120","v121","v122","v123","v124","v125","v126","v127","v128","v129",
          "v130","v131","v132","v133","v134","v135","v136","v137","v138","v139",
          "v140","v141","v142","v143","v144","v145","v146","v147","v148","v149",
          "v150","v151","v152","v153","v154","v155","v156","v157","v158","v159",
          "v160","v161","v162","v163","v164","v165","v166","v167","v168","v169",
          "v170","v171","v172","v173","v174","v175","v176","v177","v178","v179",
          "v180","s60","scc","memory");

    // ---- MLP head: y = relu(h @ w1 + b1); out = y @ w2 + b2 ----
    float4 hv4[8];
#pragma unroll
    for (int q = 0; q < 8; ++q)
        hv4[q] = ((const float4*)&hsh[elm][0])[q];
    const float* hp = (const float*)hv4;

    float y = b1[j];
#pragma unroll
    for (int k = 0; k < HDIM; ++k)
        y = fmaf(hp[k], w1[k * HDIM + j], y);
    y = fmaxf(y, 0.f);

    float v = y * w2[j];
#pragma unroll
    for (int off = 16; off >= 1; off >>= 1)
        v += __shfl_xor(v, off);        // stays within the 32-lane half

    if (j == 0) out[bb + elm] = v + b2[0];
}

extern "C" void kernel_launch(void* const* d_in, const int* in_sizes, int n_in,
                              void* d_out, int out_size, void* d_ws, size_t ws_size,
                              hipStream_t stream) {
    const int*   ids  = (const int*)d_in[0];
    const float* emb  = (const float*)d_in[1];
    const float* kern = (const float*)d_in[2];
    const float* rec  = (const float*)d_in[3];
    const float* w1   = (const float*)d_in[4];
    const float* b1   = (const float*)d_in[5];
    const float* w2   = (const float*)d_in[6];
    const float* b2   = (const float*)d_in[7];
    float* out = (float*)d_out;
    float* P2  = (float*)d_ws;   // 512 KB scratch

    precompute_P2_kernel<<<(HASH_BUCKETS * G4 + 255) / 256, 256, 0, stream>>>(
        emb, kern, P2);
    lstm_head_kernel<<<BATCH / 8, 256, 0, stream>>>(
        ids, P2, rec, w1, b1, w2, b2, out);
}

// Round 8
// 334.728 us; speedup vs baseline: 1.4050x; 1.0800x over previous
//
#include <hip/hip_runtime.h>
#include <stdint.h>

#define HASH_BUCKETS 1000
#define EMB_DIM 16
#define HDIM 32
#define G4 128   // 4*HDIM
#define TSTEPS 512
#define BATCH 4096

// ---------------------------------------------------------------------------
// Kernel 1: fold embedding through input projection, transposed layout:
// P2[bucket][j][g] = sum_e emb[bucket][e] * kernel[e][g*32 + j]
// ---------------------------------------------------------------------------
__global__ void precompute_P2_kernel(const float* __restrict__ emb,
                                     const float* __restrict__ kern,
                                     float* __restrict__ P2) {
    int idx = blockIdx.x * blockDim.x + threadIdx.x;
    if (idx >= HASH_BUCKETS * G4) return;
    int row = idx >> 7;
    int c2  = idx & 127;
    int j = c2 >> 2;
    int g = c2 & 3;
    float acc = 0.f;
#pragma unroll
    for (int e = 0; e < EMB_DIM; ++e)
        acc = fmaf(emb[row * EMB_DIM + e], kern[e * G4 + g * 32 + j], acc);
    P2[idx] = acc;
}

// ---------------------------------------------------------------------------
// Kernel 2: LSTM + MLP head, full recurrence in one asm block, physical regs.
// Round-8 layout: FULL-K per lane. Lane (j, h_) owns gate-column j of element
// elm = 2w+h_ with ALL 32 k values: R = 128 VGPRs (v32-v159), so there is NO
// cross-lane partial merge (round-7's 4 bpermutes + extra lgkm wait gone).
// Each 32-lane half is fully self-contained; h round-trips through LDS
// (write col -> read row broadcast), reads tail-issued right after the write
// (in-order DS pipe => RAW safe) to overlap their latency with bookkeeping.
// Gates: exp2-based, args clamped to <=31 (overflow-proof), the 4 z-gate
// reciprocals share ONE v_rcp via a product tree; xz is folded into the
// exp-arg FMA (xz pre-scaled by -+log2e on the prefetch path).
// Register map:
//   v32-159: R pairs, (g,k2) at v[32+32g+2k2]
//   v160-191: h[0..31] of my element
//   v192-199: z partial pairs (4 gates)
//   v200-203: xz current (pre-scaled)   v204-207: xz next (prefetch)
//   v208: addr scratch  v209: ids voffset  v210: voffset clamp
//   v211: id next  v212: id next-next  v213: h read base  v214: h write addr
//   v215: j*16  v216-229: gate scratch  v230: c  v231: h
// ---------------------------------------------------------------------------
__global__ __launch_bounds__(256)
__attribute__((amdgpu_waves_per_eu(2, 2)))
void lstm_head_kernel(const int* __restrict__ ids,
                      const float* __restrict__ P2,   // [1000][32][4]
                      const float* __restrict__ R,    // rec_kernel [32][128]
                      const float* __restrict__ w1,   // [32][32]
                      const float* __restrict__ b1,   // [32]
                      const float* __restrict__ w2,   // [32]
                      const float* __restrict__ b2,   // [1]
                      float* __restrict__ out) {
    __shared__ __align__(16) float hsh[8][HDIM];
    __shared__ float2 Rlds[2048];   // [k2:16][g:4][j:32] k-pairs of R

    const int tid = threadIdx.x;
    const int wl  = tid & 63;
    const int j   = wl & 31;
    const int h_  = wl >> 5;
    const int w   = tid >> 6;
    const int elm = 2 * w + h_;
    const int bb  = blockIdx.x * 8;

    // stage R as k-pairs into LDS: Rlds[k2*128 + g*32 + j]
    for (int idx = tid; idx < 2048; idx += 256) {
        int k2a = idx >> 7;
        int col = idx & 127;
        Rlds[idx] = make_float2(R[(2 * k2a) * G4 + col],
                                R[(2 * k2a + 1) * G4 + col]);
    }
    hsh[elm][j] = 0.f;
    __syncthreads();

    uint32_t hsh_base = (uint32_t)(uintptr_t)(&hsh[0][0]);
    uint32_t r_base   = (uint32_t)(uintptr_t)(&Rlds[0]);
    uint32_t hra   = hsh_base + (uint32_t)(elm * 128);         // row base
    uint32_t hwa   = hsh_base + (uint32_t)((elm * HDIM + j) * 4);
    uint32_t j16   = (uint32_t)(j * 16);
    uint32_t rbase = r_base + (uint32_t)(j * 8);

    const int* __restrict__ idrow = ids + (size_t)(bb + elm) * TSTEPS;
    int id0 = idrow[0];
    int id1 = idrow[1];
    float4 xz0 = *(const float4*)(P2 + id0 * G4 + j * 4);
    uint32_t voff0 = (uint32_t)(((bb + elm) * TSTEPS + 1) * 4);
    uint32_t vmax  = (uint32_t)(((bb + elm) * TSTEPS + 511) * 4);

    asm volatile(
        // ---- constants & state ----
        "s_mov_b32 s61, 0x41f80000\n\t"   // 31.0f (exp-arg clamp)
        "s_mov_b32 s62, 0xbfb8aa3b\n\t"   // -log2(e)
        "s_mov_b32 s63, 0x4038aa3b\n\t"   // 2*log2(e)
        "s_movk_i32 s60, 0x200\n\t"
        "v_mov_b32 v213, %[hra]\n\t"
        "v_mov_b32 v214, %[hwa]\n\t"
        "v_mov_b32 v215, %[j16]\n\t"
        "v_mov_b32 v209, %[voff0]\n\t"
        "v_mov_b32 v210, %[vmax]\n\t"
        "v_mov_b32 v211, %[id1]\n\t"
        "v_mov_b32 v230, 0\n\t"
        // pre-scale xz0 (i,f,o: -log2e; c: 2log2e)
        "v_mul_f32 v200, s62, %[xz0]\n\t"
        "v_mul_f32 v201, s62, %[xz1]\n\t"
        "v_mul_f32 v202, s63, %[xz2]\n\t"
        "v_mul_f32 v203, s62, %[xz3]\n\t"
        "v_mov_b32 v208, %[rbase]\n\t"
        // ---- load R: 64 x ds_read_b64, (g,k2) -> v[32+32g+2k2] ----
        "ds_read_b64 v[32:33], v208\n\t"
        "ds_read_b64 v[64:65], v208 offset:256\n\t"
        "ds_read_b64 v[96:97], v208 offset:512\n\t"
        "ds_read_b64 v[128:129], v208 offset:768\n\t"
        "ds_read_b64 v[34:35], v208 offset:1024\n\t"
        "ds_read_b64 v[66:67], v208 offset:1280\n\t"
        "ds_read_b64 v[98:99], v208 offset:1536\n\t"
        "ds_read_b64 v[130:131], v208 offset:1792\n\t"
        "ds_read_b64 v[36:37], v208 offset:2048\n\t"
        "ds_read_b64 v[68:69], v208 offset:2304\n\t"
        "ds_read_b64 v[100:101], v208 offset:2560\n\t"
        "ds_read_b64 v[132:133], v208 offset:2816\n\t"
        "ds_read_b64 v[38:39], v208 offset:3072\n\t"
        "ds_read_b64 v[70:71], v208 offset:3328\n\t"
        "ds_read_b64 v[102:103], v208 offset:3584\n\t"
        "ds_read_b64 v[134:135], v208 offset:3840\n\t"
        "ds_read_b64 v[40:41], v208 offset:4096\n\t"
        "ds_read_b64 v[72:73], v208 offset:4352\n\t"
        "ds_read_b64 v[104:105], v208 offset:4608\n\t"
        "ds_read_b64 v[136:137], v208 offset:4864\n\t"
        "ds_read_b64 v[42:43], v208 offset:5120\n\t"
        "ds_read_b64 v[74:75], v208 offset:5376\n\t"
        "ds_read_b64 v[106:107], v208 offset:5632\n\t"
        "ds_read_b64 v[138:139], v208 offset:5888\n\t"
        "ds_read_b64 v[44:45], v208 offset:6144\n\t"
        "ds_read_b64 v[76:77], v208 offset:6400\n\t"
        "ds_read_b64 v[108:109], v208 offset:6656\n\t"
        "ds_read_b64 v[140:141], v208 offset:6912\n\t"
        "ds_read_b64 v[46:47], v208 offset:7168\n\t"
        "ds_read_b64 v[78:79], v208 offset:7424\n\t"
        "ds_read_b64 v[110:111], v208 offset:7680\n\t"
        "ds_read_b64 v[142:143], v208 offset:7936\n\t"
        "ds_read_b64 v[48:49], v208 offset:8192\n\t"
        "ds_read_b64 v[80:81], v208 offset:8448\n\t"
        "ds_read_b64 v[112:113], v208 offset:8704\n\t"
        "ds_read_b64 v[144:145], v208 offset:8960\n\t"
        "ds_read_b64 v[50:51], v208 offset:9216\n\t"
        "ds_read_b64 v[82:83], v208 offset:9472\n\t"
        "ds_read_b64 v[114:115], v208 offset:9728\n\t"
        "ds_read_b64 v[146:147], v208 offset:9984\n\t"
        "ds_read_b64 v[52:53], v208 offset:10240\n\t"
        "ds_read_b64 v[84:85], v208 offset:10496\n\t"
        "ds_read_b64 v[116:117], v208 offset:10752\n\t"
        "ds_read_b64 v[148:149], v208 offset:11008\n\t"
        "ds_read_b64 v[54:55], v208 offset:11264\n\t"
        "ds_read_b64 v[86:87], v208 offset:11520\n\t"
        "ds_read_b64 v[118:119], v208 offset:11776\n\t"
        "ds_read_b64 v[150:151], v208 offset:12032\n\t"
        "ds_read_b64 v[56:57], v208 offset:12288\n\t"
        "ds_read_b64 v[88:89], v208 offset:12544\n\t"
        "ds_read_b64 v[120:121], v208 offset:12800\n\t"
        "ds_read_b64 v[152:153], v208 offset:13056\n\t"
        "ds_read_b64 v[58:59], v208 offset:13312\n\t"
        "ds_read_b64 v[90:91], v208 offset:13568\n\t"
        "ds_read_b64 v[122:123], v208 offset:13824\n\t"
        "ds_read_b64 v[154:155], v208 offset:14080\n\t"
        "ds_read_b64 v[60:61], v208 offset:14336\n\t"
        "ds_read_b64 v[92:93], v208 offset:14592\n\t"
        "ds_read_b64 v[124:125], v208 offset:14848\n\t"
        "ds_read_b64 v[156:157], v208 offset:15104\n\t"
        "ds_read_b64 v[62:63], v208 offset:15360\n\t"
        "ds_read_b64 v[94:95], v208 offset:15616\n\t"
        "ds_read_b64 v[126:127], v208 offset:15872\n\t"
        "ds_read_b64 v[158:159], v208 offset:16128\n\t"
        // ---- first h read (h=0) ----
        "ds_read_b128 v[160:163], v213\n\t"
        "ds_read_b128 v[164:167], v213 offset:16\n\t"
        "ds_read_b128 v[168:171], v213 offset:32\n\t"
        "ds_read_b128 v[172:175], v213 offset:48\n\t"
        "ds_read_b128 v[176:179], v213 offset:64\n\t"
        "ds_read_b128 v[180:183], v213 offset:80\n\t"
        "ds_read_b128 v[184:187], v213 offset:96\n\t"
        "ds_read_b128 v[188:191], v213 offset:112\n\t"

        "Llstm_%=:\n\t"
        // prefetch next xz and next-next id
        "v_lshl_add_u32 v208, v211, 9, v215\n\t"
        "global_load_dwordx4 v[204:207], v208, %[P2]\n\t"
        "v_add_u32 v209, 4, v209\n\t"
        "v_min_u32 v209, v209, v210\n\t"
        "global_load_dword v212, v209, %[IDS]\n\t"
        "s_waitcnt lgkmcnt(0)\n\t"
        // ---- matvec: 4 gate chains, 16 k-pairs ----
        "v_pk_mul_f32 v[192:193], v[160:161], v[32:33]\n\t"
        "v_pk_mul_f32 v[194:195], v[160:161], v[64:65]\n\t"
        "v_pk_mul_f32 v[196:197], v[160:161], v[96:97]\n\t"
        "v_pk_mul_f32 v[198:199], v[160:161], v[128:129]\n\t"
        "v_pk_fma_f32 v[192:193], v[162:163], v[34:35], v[192:193]\n\t"
        "v_pk_fma_f32 v[194:195], v[162:163], v[66:67], v[194:195]\n\t"
        "v_pk_fma_f32 v[196:197], v[162:163], v[98:99], v[196:197]\n\t"
        "v_pk_fma_f32 v[198:199], v[162:163], v[130:131], v[198:199]\n\t"
        "v_pk_fma_f32 v[192:193], v[164:165], v[36:37], v[192:193]\n\t"
        "v_pk_fma_f32 v[194:195], v[164:165], v[68:69], v[194:195]\n\t"
        "v_pk_fma_f32 v[196:197], v[164:165], v[100:101], v[196:197]\n\t"
        "v_pk_fma_f32 v[198:199], v[164:165], v[132:133], v[198:199]\n\t"
        "v_pk_fma_f32 v[192:193], v[166:167], v[38:39], v[192:193]\n\t"
        "v_pk_fma_f32 v[194:195], v[166:167], v[70:71], v[194:195]\n\t"
        "v_pk_fma_f32 v[196:197], v[166:167], v[102:103], v[196:197]\n\t"
        "v_pk_fma_f32 v[198:199], v[166:167], v[134:135], v[198:199]\n\t"
        "v_pk_fma_f32 v[192:193], v[168:169], v[40:41], v[192:193]\n\t"
        "v_pk_fma_f32 v[194:195], v[168:169], v[72:73], v[194:195]\n\t"
        "v_pk_fma_f32 v[196:197], v[168:169], v[104:105], v[196:197]\n\t"
        "v_pk_fma_f32 v[198:199], v[168:169], v[136:137], v[198:199]\n\t"
        "v_pk_fma_f32 v[192:193], v[170:171], v[42:43], v[192:193]\n\t"
        "v_pk_fma_f32 v[194:195], v[170:171], v[74:75], v[194:195]\n\t"
        "v_pk_fma_f32 v[196:197], v[170:171], v[106:107], v[196:197]\n\t"
        "v_pk_fma_f32 v[198:199], v[170:171], v[138:139], v[198:199]\n\t"
        "v_pk_fma_f32 v[192:193], v[172:173], v[44:45], v[192:193]\n\t"
        "v_pk_fma_f32 v[194:195], v[172:173], v[76:77], v[194:195]\n\t"
        "v_pk_fma_f32 v[196:197], v[172:173], v[108:109], v[196:197]\n\t"
        "v_pk_fma_f32 v[198:199], v[172:173], v[140:141], v[198:199]\n\t"
        "v_pk_fma_f32 v[192:193], v[174:175], v[46:47], v[192:193]\n\t"
        "v_pk_fma_f32 v[194:195], v[174:175], v[78:79], v[194:195]\n\t"
        "v_pk_fma_f32 v[196:197], v[174:175], v[110:111], v[196:197]\n\t"
        "v_pk_fma_f32 v[198:199], v[174:175], v[142:143], v[198:199]\n\t"
        "v_pk_fma_f32 v[192:193], v[176:177], v[48:49], v[192:193]\n\t"
        "v_pk_fma_f32 v[194:195], v[176:177], v[80:81], v[194:195]\n\t"
        "v_pk_fma_f32 v[196:197], v[176:177], v[112:113], v[196:197]\n\t"
        "v_pk_fma_f32 v[198:199], v[176:177], v[144:145], v[198:199]\n\t"
        "v_pk_fma_f32 v[192:193], v[178:179], v[50:51], v[192:193]\n\t"
        "v_pk_fma_f32 v[194:195], v[178:179], v[82:83], v[194:195]\n\t"
        "v_pk_fma_f32 v[196:197], v[178:179], v[114:115], v[196:197]\n\t"
        "v_pk_fma_f32 v[198:199], v[178:179], v[146:147], v[198:199]\n\t"
        "v_pk_fma_f32 v[192:193], v[180:181], v[52:53], v[192:193]\n\t"
        "v_pk_fma_f32 v[194:195], v[180:181], v[84:85], v[194:195]\n\t"
        "v_pk_fma_f32 v[196:197], v[180:181], v[116:117], v[196:197]\n\t"
        "v_pk_fma_f32 v[198:199], v[180:181], v[148:149], v[198:199]\n\t"
        "v_pk_fma_f32 v[192:193], v[182:183], v[54:55], v[192:193]\n\t"
        "v_pk_fma_f32 v[194:195], v[182:183], v[86:87], v[194:195]\n\t"
        "v_pk_fma_f32 v[196:197], v[182:183], v[118:119], v[196:197]\n\t"
        "v_pk_fma_f32 v[198:199], v[182:183], v[150:151], v[198:199]\n\t"
        "v_pk_fma_f32 v[192:193], v[184:185], v[56:57], v[192:193]\n\t"
        "v_pk_fma_f32 v[194:195], v[184:185], v[88:89], v[194:195]\n\t"
        "v_pk_fma_f32 v[196:197], v[184:185], v[120:121], v[196:197]\n\t"
        "v_pk_fma_f32 v[198:199], v[184:185], v[152:153], v[198:199]\n\t"
        "v_pk_fma_f32 v[192:193], v[186:187], v[58:59], v[192:193]\n\t"
        "v_pk_fma_f32 v[194:195], v[186:187], v[90:91], v[194:195]\n\t"
        "v_pk_fma_f32 v[196:197], v[186:187], v[122:123], v[196:197]\n\t"
        "v_pk_fma_f32 v[198:199], v[186:187], v[154:155], v[198:199]\n\t"
        "v_pk_fma_f32 v[192:193], v[188:189], v[60:61], v[192:193]\n\t"
        "v_pk_fma_f32 v[194:195], v[188:189], v[92:93], v[194:195]\n\t"
        "v_pk_fma_f32 v[196:197], v[188:189], v[124:125], v[196:197]\n\t"
        "v_pk_fma_f32 v[198:199], v[188:189], v[156:157], v[198:199]\n\t"
        "v_pk_fma_f32 v[192:193], v[190:191], v[62:63], v[192:193]\n\t"
        "v_pk_fma_f32 v[194:195], v[190:191], v[94:95], v[194:195]\n\t"
        "v_pk_fma_f32 v[196:197], v[190:191], v[126:127], v[196:197]\n\t"
        "v_pk_fma_f32 v[198:199], v[190:191], v[158:159], v[198:199]\n\t"
        // ---- collapse pairs, exp args (xz folded via fma), clamp ----
        "v_add_f32 v216, v192, v193\n\t"
        "v_add_f32 v217, v194, v195\n\t"
        "v_add_f32 v218, v196, v197\n\t"
        "v_add_f32 v219, v198, v199\n\t"
        "v_fma_f32 v216, s62, v216, v200\n\t"
        "v_fma_f32 v217, s62, v217, v201\n\t"
        "v_fma_f32 v218, s63, v218, v202\n\t"
        "v_fma_f32 v219, s62, v219, v203\n\t"
        "v_min_f32 v216, s61, v216\n\t"
        "v_min_f32 v217, s61, v217\n\t"
        "v_min_f32 v218, s61, v218\n\t"
        "v_min_f32 v219, s61, v219\n\t"
        "v_exp_f32 v216, v216\n\t"
        "v_exp_f32 v217, v217\n\t"
        "v_exp_f32 v218, v218\n\t"
        "v_exp_f32 v219, v219\n\t"
        "v_add_f32 v216, 1.0, v216\n\t"   // d_i
        "v_add_f32 v217, 1.0, v217\n\t"   // d_f
        "v_add_f32 v218, 1.0, v218\n\t"   // d_c
        "v_add_f32 v219, 1.0, v219\n\t"   // d_o
        // ---- grouped reciprocal: r = 1/(d_i d_f d_c d_o) ----
        "v_mul_f32 v220, v216, v217\n\t"  // P
        "v_mul_f32 v221, v218, v219\n\t"  // Q
        "v_mul_f32 v222, v220, v221\n\t"  // S
        "s_waitcnt vmcnt(1)\n\t"          // xz_next arrived
        "v_rcp_f32 v223, v222\n\t"
        "v_mul_f32 v204, s62, v204\n\t"   // pre-scale xz_next (fills rcp gap)
        "v_mul_f32 v205, s62, v205\n\t"
        "v_mul_f32 v206, s63, v206\n\t"
        "v_mul_f32 v207, s62, v207\n\t"
        "v_mul_f32 v224, v223, v221\n\t"  // rP = r*Q
        "v_mul_f32 v225, v223, v220\n\t"  // rQ = r*P
        "v_mul_f32 v226, v224, v217\n\t"  // i = rP*d_f
        "v_mul_f32 v227, v224, v216\n\t"  // f = rP*d_i
        "v_mul_f32 v228, v225, v219\n\t"  // rc = rQ*d_o
        "v_mul_f32 v229, v225, v218\n\t"  // o = rQ*d_c
        "v_fma_f32 v228, -2.0, v228, 1.0\n\t"   // tanh(zc)
        "v_mul_f32 v228, v226, v228\n\t"        // i*tanh(zc)
        "v_fma_f32 v230, v227, v230, v228\n\t"  // c = f*c + i*tanh(zc)
        // ---- tanh(c) ----
        "v_mul_f32 v216, s63, v230\n\t"
        "v_min_f32 v216, s61, v216\n\t"
        "v_exp_f32 v216, v216\n\t"
        "s_waitcnt vmcnt(0)\n\t"
        "v_mov_b32 v211, v212\n\t"        // shift id pipeline (fills gap)
        "v_mov_b32 v200, v204\n\t"
        "v_mov_b32 v201, v205\n\t"
        "v_add_f32 v216, 1.0, v216\n\t"
        "v_rcp_f32 v216, v216\n\t"
        "v_mov_b32 v202, v206\n\t"
        "v_mov_b32 v203, v207\n\t"
        "s_addk_i32 s60, -1\n\t"
        "v_fma_f32 v216, -2.0, v216, 1.0\n\t"   // tanh(c)
        "v_mul_f32 v231, v229, v216\n\t"        // h = o*tanh(c)
        // ---- publish h, tail-issue next h reads (in-order DS => RAW safe) ----
        "ds_write_b32 v214, v231\n\t"
        "ds_read_b128 v[160:163], v213\n\t"
        "ds_read_b128 v[164:167], v213 offset:16\n\t"
        "ds_read_b128 v[168:171], v213 offset:32\n\t"
        "ds_read_b128 v[172:175], v213 offset:48\n\t"
        "ds_read_b128 v[176:179], v213 offset:64\n\t"
        "ds_read_b128 v[180:183], v213 offset:80\n\t"
        "ds_read_b128 v[184:187], v213 offset:96\n\t"
        "ds_read_b128 v[188:191], v213 offset:112\n\t"
        "s_cmp_lg_u32 s60, 0\n\t"
        "s_cbranch_scc1 Llstm_%=\n\t"
        "s_waitcnt vmcnt(0) lgkmcnt(0)\n\t"
        :
        : [hra]"v"(hra), [hwa]"v"(hwa), [j16]"v"(j16), [rbase]"v"(rbase),
          [voff0]"v"(voff0), [vmax]"v"(vmax),
          [xz0]"v"(xz0.x), [xz1]"v"(xz0.y), [xz2]"v"(xz0.z), [xz3]"v"(xz0.w),
          [id1]"v"(id1), [P2]"s"(P2), [IDS]"s"(ids)
        : "v32","v33","v34","v35","v36","v37","v38","v39",
          "v40","v41","v42","v43","v44","v45","v46","v47","v48","v49",
          "v50","v51","v52","v53","v54","v55","v56","v57","v58","v59",
          "v60","v61","v62","v63","v64","v65","v66","v67","v68","v69",
          "v70","v71","v72","v73","v74","v75","v76","v77","v78","v79",
          "v80","v81","v82","v83","v84","v85","v86","v87","v88","v89",
          "v90","v91","v92","v93","v94","v95","v96","v97","v98","v99",
          "v100","v101","v102","v103","v104","v105","v106","v107","v108","v109",
          "v110","v111","v112","v113","v114","v115","v116","v117","v118","v119",
          "v120","v121","v122","v123","v124","v125","v126","v127","v128","v129",
          "v130","v131","v132","v133","v134","v135","v136","v137","v138","v139",
          "v140","v141","v142","v143","v144","v145","v146","v147","v148","v149",
          "v150","v151","v152","v153","v154","v155","v156","v157","v158","v159",
          "v160","v161","v162","v163","v164","v165","v166","v167","v168","v169",
          "v170","v171","v172","v173","v174","v175","v176","v177","v178","v179",
          "v180","v181","v182","v183","v184","v185","v186","v187","v188","v189",
          "v190","v191","v192","v193","v194","v195","v196","v197","v198","v199",
          "v200","v201","v202","v203","v204","v205","v206","v207","v208","v209",
          "v210","v211","v212","v213","v214","v215","v216","v217","v218","v219",
          "v220","v221","v222","v223","v224","v225","v226","v227","v228","v229",
          "v230","v231",
          "s60","s61","s62","s63","scc","memory");

    // ---- MLP head: y = relu(h @ w1 + b1); out = y @ w2 + b2 ----
    float4 hv4[8];
#pragma unroll
    for (int q = 0; q < 8; ++q)
        hv4[q] = ((const float4*)&hsh[elm][0])[q];
    const float* hp = (const float*)hv4;

    float y = b1[j];
#pragma unroll
    for (int k = 0; k < HDIM; ++k)
        y = fmaf(hp[k], w1[k * HDIM + j], y);
    y = fmaxf(y, 0.f);

    float v = y * w2[j];
#pragma unroll
    for (int off = 16; off >= 1; off >>= 1)
        v += __shfl_xor(v, off);        // stays within the 32-lane half

    if (j == 0) out[bb + elm] = v + b2[0];
}

extern "C" void kernel_launch(void* const* d_in, const int* in_sizes, int n_in,
                              void* d_out, int out_size, void* d_ws, size_t ws_size,
                              hipStream_t stream) {
    const int*   ids  = (const int*)d_in[0];
    const float* emb  = (const float*)d_in[1];
    const float* kern = (const float*)d_in[2];
    const float* rec  = (const float*)d_in[3];
    const float* w1   = (const float*)d_in[4];
    const float* b1   = (const float*)d_in[5];
    const float* w2   = (const float*)d_in[6];
    const float* b2   = (const float*)d_in[7];
    float* out = (float*)d_out;
    float* P2  = (float*)d_ws;   // 512 KB scratch

    precompute_P2_kernel<<<(HASH_BUCKETS * G4 + 255) / 256, 256, 0, stream>>>(
        emb, kern, P2);
    lstm_head_kernel<<<BATCH / 8, 256, 0, stream>>>(
        ids, P2, rec, w1, b1, w2, b2, out);
}